// Round 1
// baseline (498.926 us; speedup 1.0000x reference)
//
#include <hip/hip_runtime.h>
#include <hip/hip_bf16.h>

// VQ nearest-neighbor: N=65536 queries (32*2048), DIM=64, K=1024 codes, fp32.
// dist2[n][k] = z_sq[n] - 2*dot(z_n, c_k) + c_sq[k]; out[n] = codebook[argmin_k].
// Compute-bound on fp32 vector ALU (no fp32 MFMA on CDNA4): ~55 us roofline.

constexpr int KCODES = 1024;
constexpr int DIM = 64;
constexpr int BLOCK = 256;

// Kernel 1: per-code squared norms into workspace (1024 floats).
__global__ __launch_bounds__(64) void csq_kernel(const float* __restrict__ cb,
                                                 float* __restrict__ csq) {
    const int k = blockIdx.x;
    const float v = cb[k * DIM + threadIdx.x];
    float s = v * v;
#pragma unroll
    for (int off = 32; off > 0; off >>= 1) s += __shfl_down(s, off);
    if (threadIdx.x == 0) csq[k] = s;
}

// Kernel 2: one thread per query. Codebook reads are wave-uniform -> scalar
// loads (SGPR broadcast), z row lives in VGPRs (launch_bounds 256 so the
// 64-float array doesn't spill).
__global__ __launch_bounds__(BLOCK, 1) void vq_kernel(
    const float* __restrict__ z, const float* __restrict__ cb,
    const float* __restrict__ csq, float* __restrict__ out) {
    const int q = blockIdx.x * BLOCK + threadIdx.x;

    // Load this query's 64 floats into registers (float4 vectorized).
    float zr[DIM];
    const float* zp = z + (size_t)q * DIM;
#pragma unroll
    for (int e = 0; e < DIM; e += 4) {
        const float4 v = *(const float4*)(zp + e);
        zr[e + 0] = v.x; zr[e + 1] = v.y; zr[e + 2] = v.z; zr[e + 3] = v.w;
    }

    // z_sq (4-way partial sums, fp32 fma).
    float s0 = 0.f, s1 = 0.f, s2 = 0.f, s3 = 0.f;
#pragma unroll
    for (int e = 0; e < DIM; e += 4) {
        s0 = fmaf(zr[e + 0], zr[e + 0], s0);
        s1 = fmaf(zr[e + 1], zr[e + 1], s1);
        s2 = fmaf(zr[e + 2], zr[e + 2], s2);
        s3 = fmaf(zr[e + 3], zr[e + 3], s3);
    }
    const float zsq = (s0 + s1) + (s2 + s3);

    float best = 3.402823466e+38f;  // FLT_MAX
    int bestk = 0;

    for (int k = 0; k < KCODES; ++k) {
        const float* c = cb + k * DIM;  // wave-uniform address -> s_load
        float d0 = 0.f, d1 = 0.f, d2 = 0.f, d3 = 0.f;
#pragma unroll
        for (int e = 0; e < DIM; e += 4) {
            d0 = fmaf(zr[e + 0], c[e + 0], d0);
            d1 = fmaf(zr[e + 1], c[e + 1], d1);
            d2 = fmaf(zr[e + 2], c[e + 2], d2);
            d3 = fmaf(zr[e + 3], c[e + 3], d3);
        }
        const float dot = (d0 + d1) + (d2 + d3);
        const float dist = zsq + fmaf(-2.0f, dot, csq[k]);
        // strict < : first occurrence of min wins (matches jnp.argmin).
        if (dist < best) { best = dist; bestk = k; }
    }

    // Epilogue: gather codebook rows with coalesced writes.
    __shared__ int sbest[BLOCK];
    sbest[threadIdx.x] = bestk;
    __syncthreads();

    const size_t outBase = (size_t)blockIdx.x * BLOCK * DIM;
#pragma unroll 4
    for (int j = threadIdx.x; j < BLOCK * DIM; j += BLOCK) {
        const int qq = j >> 6;       // query within block
        const int e = j & (DIM - 1); // element within row
        out[outBase + j] = cb[sbest[qq] * DIM + e];
    }
}

extern "C" void kernel_launch(void* const* d_in, const int* in_sizes, int n_in,
                              void* d_out, int out_size, void* d_ws, size_t ws_size,
                              hipStream_t stream) {
    const float* z = (const float*)d_in[0];
    const float* cb = (const float*)d_in[1];
    float* out = (float*)d_out;
    float* csq = (float*)d_ws;  // 1024 floats of scratch

    const int nq = in_sizes[0] / DIM;  // 65536
    csq_kernel<<<KCODES, 64, 0, stream>>>(cb, csq);
    vq_kernel<<<nq / BLOCK, BLOCK, 0, stream>>>(z, cb, csq, out);
}